// Round 19
// baseline (225.234 us; speedup 1.0000x reference)
//
#include <hip/hip_runtime.h>
#include <hip/hip_bf16.h>

#define B_ 2
#define T_ 2048
#define C_ 2048
#define H_ 16
#define KH_ 4
#define D_ 128

typedef unsigned short ushort_t;
typedef __attribute__((ext_vector_type(8))) short short8;
typedef __attribute__((ext_vector_type(4))) float f32x4;

#define RSQRT_D 0.08838834764831845f
#define L2E 1.4426950408889634f
// Q pre-scale: 1/sqrt(D) * log2(e)  ->  QK^T lands in log2 units, softmax is pure exp2
#define QSCALE (0.08838834764831845f * 1.4426950408889634f)

__device__ __forceinline__ ushort_t f2b(float f) {
  union { float f; unsigned u; } v; v.f = f;
  unsigned r = v.u + 0x7fffu + ((v.u >> 16) & 1u);
  return (ushort_t)(r >> 16);
}
__device__ __forceinline__ float b2f(ushort_t u) {
  union { unsigned u; float f; } v; v.u = ((unsigned)u) << 16;
  return v.f;
}

__device__ __forceinline__ f32x4 mfma16(short8 a, short8 b, f32x4 c) {
  return __builtin_amdgcn_mfma_f32_16x16x32_bf16(a, b, c, 0, 0, 0);
}

__device__ __forceinline__ void async16(const void* g, void* l) {
  __builtin_amdgcn_global_load_lds(
      (const __attribute__((address_space(1))) void*)g,
      (__attribute__((address_space(3))) void*)l, 16, 0, 0);
}

// packed f32x2 -> bf16x2 (RTNE); dst.lo = bf16(lo), dst.hi = bf16(hi)
__device__ __forceinline__ unsigned cvtpk(float lo, float hi) {
  unsigned r;
  asm volatile("v_cvt_pk_bf16_f32 %0, %1, %2" : "=v"(r) : "v"(lo), "v"(hi));
  return r;
}

// ---------------- fused prep A: convert x -> bf16 | 3 weight transposes | rope table ----
__global__ __launch_bounds__(256) void prep_a(const float* __restrict__ x,
                                              const float* __restrict__ wq,
                                              const float* __restrict__ wkv,
                                              const float* __restrict__ wproj,
                                              const float* __restrict__ omega,
                                              ushort_t* __restrict__ xb,
                                              ushort_t* __restrict__ wqkvT,
                                              ushort_t* __restrict__ wprojT,
                                              float2* __restrict__ tab) {
  __shared__ float tile[32][33];
  int blk = blockIdx.x;
  const int tid = threadIdx.x;
  if (blk < 8192) {  // convert x (2,097,152 float4 units)
    int i = blk * 256 + tid;
    float4 v = ((const float4*)x)[i];
    ushort4 o;
    o.x = f2b(v.x); o.y = f2b(v.y); o.z = f2b(v.z); o.w = f2b(v.w);
    ((ushort4*)xb)[i] = o;
    return;
  }
  blk -= 8192;
  if (blk < 10240) {  // weight transposes: out[c][r] = bf16(in[r][c])
    const float* in;
    ushort_t* out;
    int Cc, gx, gy;
    if (blk < 4096)      { in = wq;    out = wqkvT;               Cc = 2048; gx = blk & 63;  gy = blk >> 6; }
    else if (blk < 6144) { int b2 = blk - 4096; in = wkv;  out = wqkvT + 2048 * 2048; Cc = 1024; gx = b2 & 31; gy = b2 >> 5; }
    else                 { int b2 = blk - 6144; in = wproj; out = wprojT;             Cc = 2048; gx = b2 & 63; gy = b2 >> 6; }
    const int c0 = gx * 32, r0 = gy * 32;
    const int tx = tid & 31, ty = tid >> 5;
#pragma unroll
    for (int i = 0; i < 4; i++) {
      int r = ty + i * 8;
      tile[r][tx] = in[(size_t)(r0 + r) * Cc + c0 + tx];
    }
    __syncthreads();
#pragma unroll
    for (int i = 0; i < 4; i++) {
      int r = ty + i * 8;
      out[(size_t)(c0 + r) * 2048 + r0 + tx] = f2b(tile[tx][r]);
    }
    return;
  }
  blk -= 10240;
  {  // rope table (131072 entries)
    int idx = blk * 256 + tid;
    int d = idx & 63;
    int t = idx >> 6;
    float ang = (float)t * omega[d];
    tab[idx] = make_float2(cosf(ang), sinf(ang));
  }
}

// ---------------- fused prep B: rope-Q | rope-K | V fragment pre-pack ----
__global__ __launch_bounds__(256) void prep_b(const ushort_t* __restrict__ QKVraw,
                                              const float2* __restrict__ tab,
                                              ushort_t* __restrict__ Qb,
                                              ushort_t* __restrict__ Kb,
                                              ushort_t* __restrict__ Vf) {
  int blk = blockIdx.x;
  const int tid = threadIdx.x;
  if (blk < 4096) {  // rope Q, pre-scaled by QSCALE
    int idx = blk * 256 + tid;
    int d4 = (idx & 15) * 4;
    int h = (idx >> 4) & 15;
    int t = (idx >> 8) & 2047;
    int b = idx >> 19;
    size_t in_off = (size_t)(b * 2048 + t) * 3072 + h * 128 + d4;
    ushort4 x1 = *(const ushort4*)(QKVraw + in_off);
    ushort4 x2 = *(const ushort4*)(QKVraw + in_off + 64);
    float4 csA = *(const float4*)(&tab[t * 64 + d4]);
    float4 csB = *(const float4*)(&tab[t * 64 + d4 + 2]);
    ushort4 o1, o2;
    o1.x = f2b((b2f(x1.x) * csA.x - b2f(x2.x) * csA.y) * QSCALE);
    o2.x = f2b((b2f(x1.x) * csA.y + b2f(x2.x) * csA.x) * QSCALE);
    o1.y = f2b((b2f(x1.y) * csA.z - b2f(x2.y) * csA.w) * QSCALE);
    o2.y = f2b((b2f(x1.y) * csA.w + b2f(x2.y) * csA.z) * QSCALE);
    o1.z = f2b((b2f(x1.z) * csB.x - b2f(x2.z) * csB.y) * QSCALE);
    o2.z = f2b((b2f(x1.z) * csB.y + b2f(x2.z) * csB.x) * QSCALE);
    o1.w = f2b((b2f(x1.w) * csB.z - b2f(x2.w) * csB.w) * QSCALE);
    o2.w = f2b((b2f(x1.w) * csB.w + b2f(x2.w) * csB.z) * QSCALE);
    size_t out_off = ((size_t)(b * 16 + h) * 2048 + t) * 128 + d4;
    *(ushort4*)(Qb + out_off) = o1;
    *(ushort4*)(Qb + out_off + 64) = o2;
    return;
  }
  if (blk < 5120) {  // rope K
    int idx = (blk - 4096) * 256 + tid;
    int d4 = (idx & 15) * 4;
    int kh = (idx >> 4) & 3;
    int t = (idx >> 6) & 2047;
    int b = idx >> 17;
    size_t in_off = (size_t)(b * 2048 + t) * 3072 + 2048 + kh * 128 + d4;
    ushort4 x1 = *(const ushort4*)(QKVraw + in_off);
    ushort4 x2 = *(const ushort4*)(QKVraw + in_off + 64);
    float4 csA = *(const float4*)(&tab[t * 64 + d4]);
    float4 csB = *(const float4*)(&tab[t * 64 + d4 + 2]);
    ushort4 o1, o2;
    o1.x = f2b(b2f(x1.x) * csA.x - b2f(x2.x) * csA.y);
    o2.x = f2b(b2f(x1.x) * csA.y + b2f(x2.x) * csA.x);
    o1.y = f2b(b2f(x1.y) * csA.z - b2f(x2.y) * csA.w);
    o2.y = f2b(b2f(x1.y) * csA.w + b2f(x2.y) * csA.z);
    o1.z = f2b(b2f(x1.z) * csB.x - b2f(x2.z) * csB.y);
    o2.z = f2b(b2f(x1.z) * csB.y + b2f(x2.z) * csB.x);
    o1.w = f2b(b2f(x1.w) * csB.z - b2f(x2.w) * csB.w);
    o2.w = f2b(b2f(x1.w) * csB.w + b2f(x2.w) * csB.z);
    size_t out_off = (size_t)(b * 4 + kh) * 2048 * 128 + (size_t)t * 128 + d4;
    *(ushort4*)(Kb + out_off) = o1;
    *(ushort4*)(Kb + out_off + 64) = o2;
    return;
  }
  {  // V fragment pre-pack
    int idx = (blk - 5120) * 256 + tid;
    int lane = idx & 63;
    int n = (idx >> 6) & 7;
    int hv = (idx >> 9) & 1;
    int tile = (idx >> 10) & 31;
    int z = idx >> 15;  // b*4+kh
    int b = z >> 2, kh = z & 3;
    int lr = lane & 15, lc = lane >> 4;
    int d = n * 16 + lr;
    union { ushort_t u[8]; short8 v; } out;
#pragma unroll
    for (int j = 0; j < 8; j++) {
      int tw = j >> 1, par = j & 1;
      int kl = (hv * 2 + (tw >> 1)) * 16 + lc * 4 + 2 * (tw & 1) + par;
      int t = tile * 64 + kl;
      out.u[j] = QKVraw[(size_t)(b * 2048 + t) * 3072 + 2560 + kh * 128 + d];
    }
    *(short8*)(Vf + (size_t)idx * 8) = out.v;
  }
}

// ---------------- GEMM 128x256 2-phase-per-Ktile (proj, f32 out): 16 MFMA/phase ----
__global__ __launch_bounds__(512, 1) void gemm_proj(const ushort_t* __restrict__ A,
                                                    const ushort_t* __restrict__ Bt,
                                                    float* __restrict__ C,
                                                    int M, int N, int K) {
  __shared__ __attribute__((aligned(16))) ushort_t As[2][2][4096];   // [buf][kk][128*32]
  __shared__ __attribute__((aligned(16))) ushort_t Bs[2][2][8192];   // [buf][kk][256*32]
  const int tid = threadIdx.x;
  const int lane = tid & 63;
  const int w = tid >> 6;          // 0..7
  const int lr = lane & 15, lc = lane >> 4;
  const int wm = w >> 2, wn = w & 3;
  const int nwg = gridDim.x;
  const int cpx = nwg >> 3;
  const int swz = (blockIdx.x & 7) * cpx + (blockIdx.x >> 3);
  const int bnc = N >> 8;          // N/256
  const int bm = swz / bnc, bn = swz % bnc;
  const ushort_t* Ab = A + (size_t)bm * 128 * K;
  const ushort_t* Bb = Bt + (size_t)bn * 256 * K;

  f32x4 acc[4][4];
#pragma unroll
  for (int i = 0; i < 4; i++)
#pragma unroll
    for (int j = 0; j < 4; j++) acc[i][j] = (f32x4)(0.0f);

  auto STAGE = [&](int kt, int kk) {
    const int buf = kt & 1;
    const int kbase = kt * 64 + kk * 32;
    {
      ushort_t* db = &As[buf][kk][0];
      const int u = tid, row = u >> 2, c = u & 3;
      const int lch = c ^ ((row >> 1) & 3);
      async16(Ab + (size_t)row * K + kbase + lch * 8, db + u * 8);
    }
    {
      ushort_t* db = &Bs[buf][kk][0];
      {
        const int u = tid, row = u >> 2, c = u & 3;
        const int lch = c ^ ((row >> 1) & 3);
        async16(Bb + (size_t)row * K + kbase + lch * 8, db + u * 8);
      }
      {
        const int u = 512 + tid, row = u >> 2, c = u & 3;
        const int lch = c ^ ((row >> 1) & 3);
        async16(Bb + (size_t)row * K + kbase + lch * 8, db + u * 8);
      }
    }
  };

  const int nt = K >> 6;
  STAGE(0, 0); STAGE(0, 1);
  asm volatile("s_waitcnt vmcnt(3)" ::: "memory");
  __builtin_amdgcn_s_barrier();

#pragma unroll 1
  for (int t = 0; t < nt; ++t) {
    const int buf = t & 1;
#pragma unroll
    for (int kk = 0; kk < 2; kk++) {
      const ushort_t* Ak = &As[buf][kk][0];
      const ushort_t* Bk = &Bs[buf][kk][0];
      short8 af[4], bf[4];
#pragma unroll
      for (int mf = 0; mf < 4; mf++) {
        const int row = wm * 64 + mf * 16 + lr;
        af[mf] = *(const short8*)(Ak + row * 32 + ((lc ^ ((row >> 1) & 3)) * 8));
      }
#pragma unroll
      for (int nf = 0; nf < 4; nf++) {
        const int row = wn * 64 + nf * 16 + lr;
        bf[nf] = *(const short8*)(Bk + row * 32 + ((lc ^ ((row >> 1) & 3)) * 8));
      }
      if (t + 1 < nt) STAGE(t + 1, kk);
      __builtin_amdgcn_s_barrier();
      asm volatile("s_waitcnt lgkmcnt(0)" ::: "memory");
      __builtin_amdgcn_sched_barrier(0);
      __builtin_amdgcn_s_setprio(1);
#pragma unroll
      for (int mf = 0; mf < 4; mf++)
#pragma unroll
        for (int nf = 0; nf < 4; nf++)
          acc[mf][nf] = mfma16(af[mf], bf[nf], acc[mf][nf]);
      __builtin_amdgcn_s_setprio(0);
      if (t + 1 < nt) {
        asm volatile("s_waitcnt vmcnt(3)" ::: "memory");
      } else if (kk == 0) {
        asm volatile("s_waitcnt vmcnt(0)" ::: "memory");
      }
      __builtin_amdgcn_s_barrier();
    }
  }

#pragma unroll
  for (int mf = 0; mf < 4; mf++) {
#pragma unroll
    for (int nf = 0; nf < 4; nf++) {
      const int row = bm * 128 + wm * 64 + mf * 16 + lc * 4;
      const int col = bn * 256 + wn * 64 + nf * 16 + lr;
#pragma unroll
      for (int r = 0; r < 4; r++)
        C[(size_t)(row + r) * N + col] = acc[mf][nf][r];
    }
  }
}

// ---------------- GEMM 256x192 8-phase (QKV): counted vmcnt(4), 100% CU fill ----
__global__ __launch_bounds__(512, 1) void gemm256q(const ushort_t* __restrict__ A,
                                                   const ushort_t* __restrict__ Bt,
                                                   ushort_t* __restrict__ C,
                                                   int M, int N, int K) {
  __shared__ __attribute__((aligned(16))) ushort_t As[2][2][8192];
  __shared__ __attribute__((aligned(16))) ushort_t Bs[2][2][6144];
  __shared__ __attribute__((aligned(16))) ushort_t Scr[512];
  const int tid = threadIdx.x;
  const int lane = tid & 63;
  const int w = tid >> 6;          // 0..7
  const int lr = lane & 15, lc = lane >> 4;
  const int wm = w >> 2, wn = w & 3;
  const int nwg = gridDim.x;
  const int cpx = nwg >> 3;
  const int swz = (blockIdx.x & 7) * cpx + (blockIdx.x >> 3);
  const int bnc = N / 192;
  const int bm = swz / bnc, bn = swz % bnc;
  const ushort_t* Ab = A + (size_t)bm * 256 * K;
  const ushort_t* Bb = Bt + (size_t)bn * 192 * K;

  f32x4 acc[8][3];
#pragma unroll
  for (int i = 0; i < 8; i++)
#pragma unroll
    for (int j = 0; j < 3; j++) acc[i][j] = (f32x4)(0.0f);

  auto STAGE = [&](int kt, int hid) {
    const int buf = kt & 1;
    const int kk = hid >> 1;
    const int kbase = kt * 64 + kk * 32;
    if (!(hid & 1)) {
      ushort_t* db = &As[buf][kk][0];
      {
        const int u = tid, row = u >> 2, c = u & 3;
        const int lch = c ^ ((row >> 1) & 3);
        async16(Ab + (size_t)row * K + kbase + lch * 8, db + u * 8);
      }
      {
        const int u = 512 + tid, row = u >> 2, c = u & 3;
        const int lch = c ^ ((row >> 1) & 3);
        async16(Ab + (size_t)row * K + kbase + lch * 8, db + u * 8);
      }
    } else {
      ushort_t* db = &Bs[buf][kk][0];
      {
        const int u = tid, row = u >> 2, c = u & 3;
        const int lch = c ^ ((row >> 1) & 3);
        async16(Bb + (size_t)row * K + kbase + lch * 8, db + u * 8);
      }
      if (tid < 256) {
        const int u = 512 + tid, row = u >> 2, c = u & 3;
        const int lch = c ^ ((row >> 1) & 3);
        async16(Bb + (size_t)row * K + kbase + lch * 8, db + u * 8);
      } else {
        async16(Bb + (size_t)(tid & 255) * 8, &Scr[0]);
      }
    }
  };

  const int nt = K >> 6;
  STAGE(0, 0); STAGE(0, 1); STAGE(0, 2); STAGE(0, 3);
  asm volatile("s_waitcnt vmcnt(4)" ::: "memory");
  __builtin_amdgcn_s_barrier();

#pragma unroll 1
  for (int t = 0; t < nt; ++t) {
    const int buf = t & 1;
    const ushort_t* Ak0 = &As[buf][0][0];
    const ushort_t* Ak1 = &As[buf][1][0];
    const ushort_t* Bk0 = &Bs[buf][0][0];
    const ushort_t* Bk1 = &Bs[buf][1][0];
    short8 af[4], bf[3];

    // ---- P0
#pragma unroll
    for (int nf = 0; nf < 3; nf++) {
      const int row = wn * 48 + nf * 16 + lr;
      bf[nf] = *(const short8*)(Bk0 + row * 32 + ((lc ^ ((row >> 1) & 3)) * 8));
    }
#pragma unroll
    for (int mf = 0; mf < 4; mf++) {
      const int row = wm * 128 + mf * 16 + lr;
      af[mf] = *(const short8*)(Ak0 + row * 32 + ((lc ^ ((row >> 1) & 3)) * 8));
    }
    if (t + 1 < nt) STAGE(t + 1, 0);
    __builtin_amdgcn_s_barrier();
    asm volatile("s_waitcnt lgkmcnt(0)" ::: "memory");
    __builtin_amdgcn_sched_barrier(0);
    __builtin_amdgcn_s_setprio(1);
#pragma unroll
    for (int mf = 0; mf < 4; mf++)
#pragma unroll
      for (int nf = 0; nf < 3; nf++)
        acc[mf][nf] = mfma16(af[mf], bf[nf], acc[mf][nf]);
    __builtin_amdgcn_s_setprio(0);
    __builtin_amdgcn_s_barrier();

    // ---- P1
#pragma unroll
    for (int mf = 0; mf < 4; mf++) {
      const int row = wm * 128 + 64 + mf * 16 + lr;
      af[mf] = *(const short8*)(Ak0 + row * 32 + ((lc ^ ((row >> 1) & 3)) * 8));
    }
    if (t + 1 < nt) STAGE(t + 1, 1);
    __builtin_amdgcn_s_barrier();
    asm volatile("s_waitcnt lgkmcnt(0)" ::: "memory");
    __builtin_amdgcn_sched_barrier(0);
    __builtin_amdgcn_s_setprio(1);
#pragma unroll
    for (int mf = 0; mf < 4; mf++)
#pragma unroll
      for (int nf = 0; nf < 3; nf++)
        acc[4 + mf][nf] = mfma16(af[mf], bf[nf], acc[4 + mf][nf]);
    __builtin_amdgcn_s_setprio(0);
    if (t + 1 < nt) {
      asm volatile("s_waitcnt vmcnt(4)" ::: "memory");
    } else {
      asm volatile("s_waitcnt vmcnt(0)" ::: "memory");
    }
    __builtin_amdgcn_s_barrier();

    // ---- P2
#pragma unroll
    for (int nf = 0; nf < 3; nf++) {
      const int row = wn * 48 + nf * 16 + lr;
      bf[nf] = *(const short8*)(Bk1 + row * 32 + ((lc ^ ((row >> 1) & 3)) * 8));
    }
#pragma unroll
    for (int mf = 0; mf < 4; mf++) {
      const int row = wm * 128 + mf * 16 + lr;
      af[mf] = *(const short8*)(Ak1 + row * 32 + ((lc ^ ((row >> 1) & 3)) * 8));
    }
    if (t + 1 < nt) STAGE(t + 1, 2);
    __builtin_amdgcn_s_barrier();
    asm volatile("s_waitcnt lgkmcnt(0)" ::: "memory");
    __builtin_amdgcn_sched_barrier(0);
    __builtin_amdgcn_s_setprio(1);
#pragma unroll
    for (int mf = 0; mf < 4; mf++)
#pragma unroll
      for (int nf = 0; nf < 3; nf++)
        acc[mf][nf] = mfma16(af[mf], bf[nf], acc[mf][nf]);
    __builtin_amdgcn_s_setprio(0);
    __builtin_amdgcn_s_barrier();

    // ---- P3
#pragma unroll
    for (int mf = 0; mf < 4; mf++) {
      const int row = wm * 128 + 64 + mf * 16 + lr;
      af[mf] = *(const short8*)(Ak1 + row * 32 + ((lc ^ ((row >> 1) & 3)) * 8));
    }
    if (t + 1 < nt) STAGE(t + 1, 3);
    __builtin_amdgcn_s_barrier();
    asm volatile("s_waitcnt lgkmcnt(0)" ::: "memory");
    __builtin_amdgcn_sched_barrier(0);
    __builtin_amdgcn_s_setprio(1);
#pragma unroll
    for (int mf = 0; mf < 4; mf++)
#pragma unroll
      for (int nf = 0; nf < 3; nf++)
        acc[4 + mf][nf] = mfma16(af[mf], bf[nf], acc[4 + mf][nf]);
    __builtin_amdgcn_s_setprio(0);
    if (t + 1 < nt) {
      asm volatile("s_waitcnt vmcnt(4)" ::: "memory");
    }
    __builtin_amdgcn_s_barrier();
  }

#pragma unroll
  for (int mfp = 0; mfp < 8; mfp++) {
#pragma unroll
    for (int nf = 0; nf < 3; nf++) {
      const int row = bm * 256 + wm * 128 + mfp * 16 + lc * 4;
      const int col = bn * 192 + wn * 48 + nf * 16 + lr;
#pragma unroll
      for (int r = 0; r < 4; r++)
        C[(size_t)(row + r) * N + col] = f2b(acc[mfp][nf][r]);
    }
  }
}

// ---------------- flash attention (causal GQA) — QBLK=256, 8 waves, 1 block/CU ----
// 512 threads = 8 waves; wave w owns rows q0w = qc*256 + w*32 (two 16-row frags,
// inner loop identical to the proven R9 config). Grid 256 blocks (8 qc x 16 h x 2 b)
// = exactly 1/CU, ALL resident -> heavy chunks run at a SUSTAINED 2 waves/SIMD
// (R18's paired config degraded to 1 wave/SIMD once the light partner exited).
// nt = 4*qc+4 tiles of 64. Masked waves still hit every __syncthreads (continue
// is after the barrier).
__global__ __launch_bounds__(512, 2) void attn_k(const ushort_t* __restrict__ Qb,
                                                 const ushort_t* __restrict__ Kb,
                                                 const ushort_t* __restrict__ Vf,
                                                 ushort_t* __restrict__ Yb) {
  __shared__ __attribute__((aligned(16))) ushort_t Ks[2][64 * 128];  // 32 KB
  const int tid = threadIdx.x;
  const int lane = tid & 63;
  const int w = tid >> 6;          // 0..7
  const int lr = lane & 15, lc = lane >> 4;
  const int h = blockIdx.y;
  const int b = blockIdx.z;
  const int kh = h >> 2;
  const int qc = blockIdx.x;       // 0..7 (all blocks resident; order irrelevant)
  const int q0w = qc * 256 + w * 32;

  const ushort_t* Qp = Qb + (size_t)(b * 16 + h) * T_ * D_;
  const ushort_t* Kp = Kb + (size_t)(b * 4 + kh) * T_ * D_;
  const ushort_t* Vfb = Vf + (size_t)(b * 4 + kh) * 262144;

  // staging: 512 threads cover 1024 units (64 rows x 16 slots) in 2 loads
  const int st_row = tid >> 4;     // 0..31, +i*32
  const int st_slot = tid & 15;

  short8 qf[2][4];
#pragma unroll
  for (int f = 0; f < 2; f++)
#pragma unroll
    for (int c = 0; c < 4; c++)
      qf[f][c] = *(const short8*)(Qp + (size_t)(q0w + f * 16 + lr) * D_ + c * 32 + lc * 8);

  f32x4 o[2][8];
#pragma unroll
  for (int f = 0; f < 2; f++)
#pragma unroll
    for (int n = 0; n < 8; n++) o[f][n] = (f32x4)(0.0f);
  float m[2] = {-1e30f, -1e30f}, l[2] = {0.0f, 0.0f};

  const int nt = 4 * qc + 4;       // kv tiles of 64 covering rows qc*256..+255

#pragma unroll
  for (int i = 0; i < 2; i++) {
    int row = i * 32 + st_row;
    async16(Kp + (size_t)row * D_ + (((st_slot - row) & 15) * 8),
            &Ks[0][0] + row * 128 + st_slot * 8);
  }

#pragma unroll 1
  for (int ti = 0; ti < nt; ti++) {
    __syncthreads();
    const int kv0 = ti * 64;
    if (ti + 1 < nt) {
      const ushort_t* Kn = Kp + (size_t)(kv0 + 64) * D_;
      ushort_t* dst = &Ks[(ti + 1) & 1][0];
#pragma unroll
      for (int i = 0; i < 2; i++) {
        int row = i * 32 + st_row;
        async16(Kn + (size_t)row * D_ + (((st_slot - row) & 15) * 8),
                dst + row * 128 + st_slot * 8);
      }
    }
    if (kv0 > q0w + 31) continue;  // wave fully masked; barriers already passed
    const ushort_t* Kl = &Ks[ti & 1][0];
    const ushort_t* Vt0 = Vfb + (size_t)(ti * 2) * 4096;
    short8 vr0[8];
#pragma unroll
    for (int n = 0; n < 8; n++)
      vr0[n] = *(const short8*)(Vt0 + n * 512 + lane * 8);
    f32x4 s[2][4];
#pragma unroll
    for (int f = 0; f < 2; f++)
#pragma unroll
      for (int kj = 0; kj < 4; kj++) s[f][kj] = (f32x4)(0.0f);
    __builtin_amdgcn_s_setprio(1);
#pragma unroll
    for (int c = 0; c < 4; c++) {
      short8 kf[4];
#pragma unroll
      for (int kj = 0; kj < 4; kj++)
        kf[kj] = *(const short8*)(Kl + (kj * 16 + lr) * 128 + (((c * 4 + lc + lr) & 15) * 8));
#pragma unroll
      for (int f = 0; f < 2; f++)
#pragma unroll
        for (int kj = 0; kj < 4; kj++)
          s[f][kj] = mfma16(kf[kj], qf[f][c], s[f][kj]);
    }
    __builtin_amdgcn_s_setprio(0);
    const ushort_t* Vt1 = Vfb + (size_t)(ti * 2 + 1) * 4096;
    short8 vr1[8];
#pragma unroll
    for (int n = 0; n < 8; n++)
      vr1[n] = *(const short8*)(Vt1 + n * 512 + lane * 8);
    const bool maskt = (kv0 + 63 > q0w);
    union { unsigned u[4]; short8 v; } pa0[2], pa1[2];
#pragma unroll
    for (int f = 0; f < 2; f++) {
      const int q = q0w + f * 16 + lr;
      float pv[16];
      float mx = -1e30f;
      if (maskt) {
#pragma unroll
        for (int kj = 0; kj < 4; kj++)
#pragma unroll
          for (int r = 0; r < 4; r++) {
            float a = s[f][kj][r];
            if (kv0 + kj * 16 + lc * 4 + r > q) a = -1e30f;
            pv[kj * 4 + r] = a;
            mx = fmaxf(mx, a);
          }
      } else {
#pragma unroll
        for (int kj = 0; kj < 4; kj++)
#pragma unroll
          for (int r = 0; r < 4; r++) {
            float a = s[f][kj][r];
            pv[kj * 4 + r] = a;
            mx = fmaxf(mx, a);
          }
      }
      mx = fmaxf(mx, __shfl_xor(mx, 16));
      mx = fmaxf(mx, __shfl_xor(mx, 32));
      const bool need = __any(mx > m[f] + 8.0f);
      const float mn = need ? fmaxf(m[f], mx) : m[f];
      float rs = 0.0f;
#pragma unroll
      for (int i = 0; i < 16; i++) {
        pv[i] = exp2f(pv[i] - mn);
        rs += pv[i];
      }
      rs += __shfl_xor(rs, 16);
      rs += __shfl_xor(rs, 32);
#pragma unroll
      for (int kj = 0; kj < 2; kj++) {
        pa0[f].u[kj * 2] = cvtpk(pv[kj * 4], pv[kj * 4 + 1]);
        pa0[f].u[kj * 2 + 1] = cvtpk(pv[kj * 4 + 2], pv[kj * 4 + 3]);
        pa1[f].u[kj * 2] = cvtpk(pv[8 + kj * 4], pv[8 + kj * 4 + 1]);
        pa1[f].u[kj * 2 + 1] = cvtpk(pv[8 + kj * 4 + 2], pv[8 + kj * 4 + 3]);
      }
      if (need) {
        float al = exp2f(m[f] - mn);
        m[f] = mn;
        l[f] = l[f] * al + rs;
        float alT[4];
#pragma unroll
        for (int r = 0; r < 4; r++)
          alT[r] = __shfl(al, (lane & 48) | (lc * 4 + r));
#pragma unroll
        for (int n = 0; n < 8; n++)
#pragma unroll
          for (int r = 0; r < 4; r++) o[f][n][r] *= alT[r];
      } else {
        l[f] += rs;
      }
    }
    __builtin_amdgcn_s_setprio(1);
#pragma unroll
    for (int n = 0; n < 8; n++) {
      o[0][n] = mfma16(pa0[0].v, vr0[n], o[0][n]);
      o[1][n] = mfma16(pa0[1].v, vr0[n], o[1][n]);
    }
#pragma unroll
    for (int n = 0; n < 8; n++) {
      o[0][n] = mfma16(pa1[0].v, vr1[n], o[0][n]);
      o[1][n] = mfma16(pa1[1].v, vr1[n], o[1][n]);
    }
    __builtin_amdgcn_s_setprio(0);
  }
#pragma unroll
  for (int f = 0; f < 2; f++) {
    float inv = 1.0f / l[f];
    float invT[4];
#pragma unroll
    for (int r = 0; r < 4; r++)
      invT[r] = __shfl(inv, (lane & 48) | (lc * 4 + r));
#pragma unroll
    for (int n = 0; n < 8; n++)
#pragma unroll
      for (int r = 0; r < 4; r++) {
        int qo = q0w + f * 16 + lc * 4 + r;
        int d = n * 16 + lr;
        Yb[(size_t)(b * T_ + qo) * 2048 + h * 128 + d] = f2b(o[f][n][r] * invT[r]);
      }
  }
}

// ---------------- launch ----------------

extern "C" void kernel_launch(void* const* d_in, const int* in_sizes, int n_in,
                              void* d_out, int out_size, void* d_ws, size_t ws_size,
                              hipStream_t stream) {
  (void)in_sizes; (void)n_in; (void)out_size; (void)ws_size;
  const float* x = (const float*)d_in[0];
  const float* wq = (const float*)d_in[1];
  const float* wkv = (const float*)d_in[2];
  const float* wproj = (const float*)d_in[3];
  const float* omega = (const float*)d_in[4];
  float* out = (float*)d_out;
  char* ws = (char*)d_ws;

  ushort_t* xb     = (ushort_t*)(ws + 0);          // 4096x2048 bf16 = 16.8MB
  ushort_t* wqkvT  = (ushort_t*)(ws + 16777216);   // [3072][2048] bf16 (wqT then wkvT)
  ushort_t* wprojT = (ushort_t*)(ws + 29360128);   // 2048x2048 bf16
  ushort_t* QKVraw = (ushort_t*)(ws + 37748736);   // 4096x3072 bf16 = 25.2MB
  ushort_t* Qb     = (ushort_t*)(ws + 62914560);   // [b][h][t][d] bf16
  ushort_t* Kb     = (ushort_t*)(ws + 79691776);   // [b][kh][t][d] bf16
  ushort_t* Vf     = (ushort_t*)(ws + 83886080);   // V fragment-packed, 4MB
  ushort_t* Yb     = (ushort_t*)(ws + 88080384);   // 4096x2048 bf16
  float2*   tab    = (float2*)(ws + 104857600);    // 2048x64 float2 = 1MB

  // fused prep: convert | 3 transposes | rope table
  prep_a<<<18944, 256, 0, stream>>>(x, wq, wkv, wproj, omega, xb, wqkvT, wprojT, tab);

  // merged QKV projection via 256x192 8-phase (256 blocks = 100% CU fill)
  gemm256q<<<256, 512, 0, stream>>>(xb, wqkvT, QKVraw, 4096, 3072, 2048);

  // fused prep: rope-Q | rope-K | V fragment pre-pack
  prep_b<<<6144, 256, 0, stream>>>(QKVraw, tab, Qb, Kb, Vf);

  // attention: QBLK=256, 8 waves/block, 256 blocks = 1/CU (sustained 2 waves/SIMD)
  attn_k<<<dim3(8, 16, 2), 512, 0, stream>>>(Qb, Kb, Vf, Yb);

  // output projection via 128x256 2-phase-per-Ktile (256 blocks, 16 MFMA/phase)
  gemm_proj<<<256, 512, 0, stream>>>(Yb, wprojT, out, 4096, 2048, 2048);
}

// Round 20
// 204.622 us; speedup vs baseline: 1.1007x; 1.1007x over previous
//
#include <hip/hip_runtime.h>
#include <hip/hip_bf16.h>

#define B_ 2
#define T_ 2048
#define C_ 2048
#define H_ 16
#define KH_ 4
#define D_ 128

typedef unsigned short ushort_t;
typedef __attribute__((ext_vector_type(8))) short short8;
typedef __attribute__((ext_vector_type(4))) float f32x4;

#define RSQRT_D 0.08838834764831845f
#define L2E 1.4426950408889634f
// Q pre-scale: 1/sqrt(D) * log2(e)  ->  QK^T lands in log2 units, softmax is pure exp2
#define QSCALE (0.08838834764831845f * 1.4426950408889634f)

__device__ __forceinline__ ushort_t f2b(float f) {
  union { float f; unsigned u; } v; v.f = f;
  unsigned r = v.u + 0x7fffu + ((v.u >> 16) & 1u);
  return (ushort_t)(r >> 16);
}
__device__ __forceinline__ float b2f(ushort_t u) {
  union { unsigned u; float f; } v; v.u = ((unsigned)u) << 16;
  return v.f;
}

__device__ __forceinline__ f32x4 mfma16(short8 a, short8 b, f32x4 c) {
  return __builtin_amdgcn_mfma_f32_16x16x32_bf16(a, b, c, 0, 0, 0);
}

__device__ __forceinline__ void async16(const void* g, void* l) {
  __builtin_amdgcn_global_load_lds(
      (const __attribute__((address_space(1))) void*)g,
      (__attribute__((address_space(3))) void*)l, 16, 0, 0);
}

// packed f32x2 -> bf16x2 (RTNE); dst.lo = bf16(lo), dst.hi = bf16(hi)
__device__ __forceinline__ unsigned cvtpk(float lo, float hi) {
  unsigned r;
  asm volatile("v_cvt_pk_bf16_f32 %0, %1, %2" : "=v"(r) : "v"(lo), "v"(hi));
  return r;
}

// ---------------- fused prep A: convert x -> bf16 | 3 weight transposes | rope table ----
__global__ __launch_bounds__(256) void prep_a(const float* __restrict__ x,
                                              const float* __restrict__ wq,
                                              const float* __restrict__ wkv,
                                              const float* __restrict__ wproj,
                                              const float* __restrict__ omega,
                                              ushort_t* __restrict__ xb,
                                              ushort_t* __restrict__ wqkvT,
                                              ushort_t* __restrict__ wprojT,
                                              float2* __restrict__ tab) {
  __shared__ float tile[32][33];
  int blk = blockIdx.x;
  const int tid = threadIdx.x;
  if (blk < 8192) {  // convert x (2,097,152 float4 units)
    int i = blk * 256 + tid;
    float4 v = ((const float4*)x)[i];
    ushort4 o;
    o.x = f2b(v.x); o.y = f2b(v.y); o.z = f2b(v.z); o.w = f2b(v.w);
    ((ushort4*)xb)[i] = o;
    return;
  }
  blk -= 8192;
  if (blk < 10240) {  // weight transposes: out[c][r] = bf16(in[r][c])
    const float* in;
    ushort_t* out;
    int Cc, gx, gy;
    if (blk < 4096)      { in = wq;    out = wqkvT;               Cc = 2048; gx = blk & 63;  gy = blk >> 6; }
    else if (blk < 6144) { int b2 = blk - 4096; in = wkv;  out = wqkvT + 2048 * 2048; Cc = 1024; gx = b2 & 31; gy = b2 >> 5; }
    else                 { int b2 = blk - 6144; in = wproj; out = wprojT;             Cc = 2048; gx = b2 & 63; gy = b2 >> 6; }
    const int c0 = gx * 32, r0 = gy * 32;
    const int tx = tid & 31, ty = tid >> 5;
#pragma unroll
    for (int i = 0; i < 4; i++) {
      int r = ty + i * 8;
      tile[r][tx] = in[(size_t)(r0 + r) * Cc + c0 + tx];
    }
    __syncthreads();
#pragma unroll
    for (int i = 0; i < 4; i++) {
      int r = ty + i * 8;
      out[(size_t)(c0 + r) * 2048 + r0 + tx] = f2b(tile[tx][r]);
    }
    return;
  }
  blk -= 10240;
  {  // rope table (131072 entries)
    int idx = blk * 256 + tid;
    int d = idx & 63;
    int t = idx >> 6;
    float ang = (float)t * omega[d];
    tab[idx] = make_float2(cosf(ang), sinf(ang));
  }
}

// ---------------- fused prep B: rope-Q | rope-K | V fragment pre-pack ----
__global__ __launch_bounds__(256) void prep_b(const ushort_t* __restrict__ QKVraw,
                                              const float2* __restrict__ tab,
                                              ushort_t* __restrict__ Qb,
                                              ushort_t* __restrict__ Kb,
                                              ushort_t* __restrict__ Vf) {
  int blk = blockIdx.x;
  const int tid = threadIdx.x;
  if (blk < 4096) {  // rope Q, pre-scaled by QSCALE
    int idx = blk * 256 + tid;
    int d4 = (idx & 15) * 4;
    int h = (idx >> 4) & 15;
    int t = (idx >> 8) & 2047;
    int b = idx >> 19;
    size_t in_off = (size_t)(b * 2048 + t) * 3072 + h * 128 + d4;
    ushort4 x1 = *(const ushort4*)(QKVraw + in_off);
    ushort4 x2 = *(const ushort4*)(QKVraw + in_off + 64);
    float4 csA = *(const float4*)(&tab[t * 64 + d4]);
    float4 csB = *(const float4*)(&tab[t * 64 + d4 + 2]);
    ushort4 o1, o2;
    o1.x = f2b((b2f(x1.x) * csA.x - b2f(x2.x) * csA.y) * QSCALE);
    o2.x = f2b((b2f(x1.x) * csA.y + b2f(x2.x) * csA.x) * QSCALE);
    o1.y = f2b((b2f(x1.y) * csA.z - b2f(x2.y) * csA.w) * QSCALE);
    o2.y = f2b((b2f(x1.y) * csA.w + b2f(x2.y) * csA.z) * QSCALE);
    o1.z = f2b((b2f(x1.z) * csB.x - b2f(x2.z) * csB.y) * QSCALE);
    o2.z = f2b((b2f(x1.z) * csB.y + b2f(x2.z) * csB.x) * QSCALE);
    o1.w = f2b((b2f(x1.w) * csB.z - b2f(x2.w) * csB.w) * QSCALE);
    o2.w = f2b((b2f(x1.w) * csB.w + b2f(x2.w) * csB.z) * QSCALE);
    size_t out_off = ((size_t)(b * 16 + h) * 2048 + t) * 128 + d4;
    *(ushort4*)(Qb + out_off) = o1;
    *(ushort4*)(Qb + out_off + 64) = o2;
    return;
  }
  if (blk < 5120) {  // rope K
    int idx = (blk - 4096) * 256 + tid;
    int d4 = (idx & 15) * 4;
    int kh = (idx >> 4) & 3;
    int t = (idx >> 6) & 2047;
    int b = idx >> 17;
    size_t in_off = (size_t)(b * 2048 + t) * 3072 + 2048 + kh * 128 + d4;
    ushort4 x1 = *(const ushort4*)(QKVraw + in_off);
    ushort4 x2 = *(const ushort4*)(QKVraw + in_off + 64);
    float4 csA = *(const float4*)(&tab[t * 64 + d4]);
    float4 csB = *(const float4*)(&tab[t * 64 + d4 + 2]);
    ushort4 o1, o2;
    o1.x = f2b(b2f(x1.x) * csA.x - b2f(x2.x) * csA.y);
    o2.x = f2b(b2f(x1.x) * csA.y + b2f(x2.x) * csA.x);
    o1.y = f2b(b2f(x1.y) * csA.z - b2f(x2.y) * csA.w);
    o2.y = f2b(b2f(x1.y) * csA.w + b2f(x2.y) * csA.z);
    o1.z = f2b(b2f(x1.z) * csB.x - b2f(x2.z) * csB.y);
    o2.z = f2b(b2f(x1.z) * csB.y + b2f(x2.z) * csB.x);
    o1.w = f2b(b2f(x1.w) * csB.z - b2f(x2.w) * csB.w);
    o2.w = f2b(b2f(x1.w) * csB.w + b2f(x2.w) * csB.z);
    size_t out_off = (size_t)(b * 4 + kh) * 2048 * 128 + (size_t)t * 128 + d4;
    *(ushort4*)(Kb + out_off) = o1;
    *(ushort4*)(Kb + out_off + 64) = o2;
    return;
  }
  {  // V fragment pre-pack
    int idx = (blk - 5120) * 256 + tid;
    int lane = idx & 63;
    int n = (idx >> 6) & 7;
    int hv = (idx >> 9) & 1;
    int tile = (idx >> 10) & 31;
    int z = idx >> 15;  // b*4+kh
    int b = z >> 2, kh = z & 3;
    int lr = lane & 15, lc = lane >> 4;
    int d = n * 16 + lr;
    union { ushort_t u[8]; short8 v; } out;
#pragma unroll
    for (int j = 0; j < 8; j++) {
      int tw = j >> 1, par = j & 1;
      int kl = (hv * 2 + (tw >> 1)) * 16 + lc * 4 + 2 * (tw & 1) + par;
      int t = tile * 64 + kl;
      out.u[j] = QKVraw[(size_t)(b * 2048 + t) * 3072 + 2560 + kh * 128 + d];
    }
    *(short8*)(Vf + (size_t)idx * 8) = out.v;
  }
}

// ---------------- GEMM 128x256 2-phase-per-Ktile (proj, f32 out): 16 MFMA/phase ----
__global__ __launch_bounds__(512, 1) void gemm_proj(const ushort_t* __restrict__ A,
                                                    const ushort_t* __restrict__ Bt,
                                                    float* __restrict__ C,
                                                    int M, int N, int K) {
  __shared__ __attribute__((aligned(16))) ushort_t As[2][2][4096];   // [buf][kk][128*32]
  __shared__ __attribute__((aligned(16))) ushort_t Bs[2][2][8192];   // [buf][kk][256*32]
  const int tid = threadIdx.x;
  const int lane = tid & 63;
  const int w = tid >> 6;          // 0..7
  const int lr = lane & 15, lc = lane >> 4;
  const int wm = w >> 2, wn = w & 3;
  const int nwg = gridDim.x;
  const int cpx = nwg >> 3;
  const int swz = (blockIdx.x & 7) * cpx + (blockIdx.x >> 3);
  const int bnc = N >> 8;          // N/256
  const int bm = swz / bnc, bn = swz % bnc;
  const ushort_t* Ab = A + (size_t)bm * 128 * K;
  const ushort_t* Bb = Bt + (size_t)bn * 256 * K;

  f32x4 acc[4][4];
#pragma unroll
  for (int i = 0; i < 4; i++)
#pragma unroll
    for (int j = 0; j < 4; j++) acc[i][j] = (f32x4)(0.0f);

  auto STAGE = [&](int kt, int kk) {
    const int buf = kt & 1;
    const int kbase = kt * 64 + kk * 32;
    {
      ushort_t* db = &As[buf][kk][0];
      const int u = tid, row = u >> 2, c = u & 3;
      const int lch = c ^ ((row >> 1) & 3);
      async16(Ab + (size_t)row * K + kbase + lch * 8, db + u * 8);
    }
    {
      ushort_t* db = &Bs[buf][kk][0];
      {
        const int u = tid, row = u >> 2, c = u & 3;
        const int lch = c ^ ((row >> 1) & 3);
        async16(Bb + (size_t)row * K + kbase + lch * 8, db + u * 8);
      }
      {
        const int u = 512 + tid, row = u >> 2, c = u & 3;
        const int lch = c ^ ((row >> 1) & 3);
        async16(Bb + (size_t)row * K + kbase + lch * 8, db + u * 8);
      }
    }
  };

  const int nt = K >> 6;
  STAGE(0, 0); STAGE(0, 1);
  asm volatile("s_waitcnt vmcnt(3)" ::: "memory");
  __builtin_amdgcn_s_barrier();

#pragma unroll 1
  for (int t = 0; t < nt; ++t) {
    const int buf = t & 1;
#pragma unroll
    for (int kk = 0; kk < 2; kk++) {
      const ushort_t* Ak = &As[buf][kk][0];
      const ushort_t* Bk = &Bs[buf][kk][0];
      short8 af[4], bf[4];
#pragma unroll
      for (int mf = 0; mf < 4; mf++) {
        const int row = wm * 64 + mf * 16 + lr;
        af[mf] = *(const short8*)(Ak + row * 32 + ((lc ^ ((row >> 1) & 3)) * 8));
      }
#pragma unroll
      for (int nf = 0; nf < 4; nf++) {
        const int row = wn * 64 + nf * 16 + lr;
        bf[nf] = *(const short8*)(Bk + row * 32 + ((lc ^ ((row >> 1) & 3)) * 8));
      }
      if (t + 1 < nt) STAGE(t + 1, kk);
      __builtin_amdgcn_s_barrier();
      asm volatile("s_waitcnt lgkmcnt(0)" ::: "memory");
      __builtin_amdgcn_sched_barrier(0);
      __builtin_amdgcn_s_setprio(1);
#pragma unroll
      for (int mf = 0; mf < 4; mf++)
#pragma unroll
        for (int nf = 0; nf < 4; nf++)
          acc[mf][nf] = mfma16(af[mf], bf[nf], acc[mf][nf]);
      __builtin_amdgcn_s_setprio(0);
      if (t + 1 < nt) {
        asm volatile("s_waitcnt vmcnt(3)" ::: "memory");
      } else if (kk == 0) {
        asm volatile("s_waitcnt vmcnt(0)" ::: "memory");
      }
      __builtin_amdgcn_s_barrier();
    }
  }

#pragma unroll
  for (int mf = 0; mf < 4; mf++) {
#pragma unroll
    for (int nf = 0; nf < 4; nf++) {
      const int row = bm * 128 + wm * 64 + mf * 16 + lc * 4;
      const int col = bn * 256 + wn * 64 + nf * 16 + lr;
#pragma unroll
      for (int r = 0; r < 4; r++)
        C[(size_t)(row + r) * N + col] = acc[mf][nf][r];
    }
  }
}

// ---------------- GEMM 256x192 8-phase (QKV): counted vmcnt(4), 100% CU fill ----
__global__ __launch_bounds__(512, 1) void gemm256q(const ushort_t* __restrict__ A,
                                                   const ushort_t* __restrict__ Bt,
                                                   ushort_t* __restrict__ C,
                                                   int M, int N, int K) {
  __shared__ __attribute__((aligned(16))) ushort_t As[2][2][8192];
  __shared__ __attribute__((aligned(16))) ushort_t Bs[2][2][6144];
  __shared__ __attribute__((aligned(16))) ushort_t Scr[512];
  const int tid = threadIdx.x;
  const int lane = tid & 63;
  const int w = tid >> 6;          // 0..7
  const int lr = lane & 15, lc = lane >> 4;
  const int wm = w >> 2, wn = w & 3;
  const int nwg = gridDim.x;
  const int cpx = nwg >> 3;
  const int swz = (blockIdx.x & 7) * cpx + (blockIdx.x >> 3);
  const int bnc = N / 192;
  const int bm = swz / bnc, bn = swz % bnc;
  const ushort_t* Ab = A + (size_t)bm * 256 * K;
  const ushort_t* Bb = Bt + (size_t)bn * 192 * K;

  f32x4 acc[8][3];
#pragma unroll
  for (int i = 0; i < 8; i++)
#pragma unroll
    for (int j = 0; j < 3; j++) acc[i][j] = (f32x4)(0.0f);

  auto STAGE = [&](int kt, int hid) {
    const int buf = kt & 1;
    const int kk = hid >> 1;
    const int kbase = kt * 64 + kk * 32;
    if (!(hid & 1)) {
      ushort_t* db = &As[buf][kk][0];
      {
        const int u = tid, row = u >> 2, c = u & 3;
        const int lch = c ^ ((row >> 1) & 3);
        async16(Ab + (size_t)row * K + kbase + lch * 8, db + u * 8);
      }
      {
        const int u = 512 + tid, row = u >> 2, c = u & 3;
        const int lch = c ^ ((row >> 1) & 3);
        async16(Ab + (size_t)row * K + kbase + lch * 8, db + u * 8);
      }
    } else {
      ushort_t* db = &Bs[buf][kk][0];
      {
        const int u = tid, row = u >> 2, c = u & 3;
        const int lch = c ^ ((row >> 1) & 3);
        async16(Bb + (size_t)row * K + kbase + lch * 8, db + u * 8);
      }
      if (tid < 256) {
        const int u = 512 + tid, row = u >> 2, c = u & 3;
        const int lch = c ^ ((row >> 1) & 3);
        async16(Bb + (size_t)row * K + kbase + lch * 8, db + u * 8);
      } else {
        async16(Bb + (size_t)(tid & 255) * 8, &Scr[0]);
      }
    }
  };

  const int nt = K >> 6;
  STAGE(0, 0); STAGE(0, 1); STAGE(0, 2); STAGE(0, 3);
  asm volatile("s_waitcnt vmcnt(4)" ::: "memory");
  __builtin_amdgcn_s_barrier();

#pragma unroll 1
  for (int t = 0; t < nt; ++t) {
    const int buf = t & 1;
    const ushort_t* Ak0 = &As[buf][0][0];
    const ushort_t* Ak1 = &As[buf][1][0];
    const ushort_t* Bk0 = &Bs[buf][0][0];
    const ushort_t* Bk1 = &Bs[buf][1][0];
    short8 af[4], bf[3];

    // ---- P0
#pragma unroll
    for (int nf = 0; nf < 3; nf++) {
      const int row = wn * 48 + nf * 16 + lr;
      bf[nf] = *(const short8*)(Bk0 + row * 32 + ((lc ^ ((row >> 1) & 3)) * 8));
    }
#pragma unroll
    for (int mf = 0; mf < 4; mf++) {
      const int row = wm * 128 + mf * 16 + lr;
      af[mf] = *(const short8*)(Ak0 + row * 32 + ((lc ^ ((row >> 1) & 3)) * 8));
    }
    if (t + 1 < nt) STAGE(t + 1, 0);
    __builtin_amdgcn_s_barrier();
    asm volatile("s_waitcnt lgkmcnt(0)" ::: "memory");
    __builtin_amdgcn_sched_barrier(0);
    __builtin_amdgcn_s_setprio(1);
#pragma unroll
    for (int mf = 0; mf < 4; mf++)
#pragma unroll
      for (int nf = 0; nf < 3; nf++)
        acc[mf][nf] = mfma16(af[mf], bf[nf], acc[mf][nf]);
    __builtin_amdgcn_s_setprio(0);
    __builtin_amdgcn_s_barrier();

    // ---- P1
#pragma unroll
    for (int mf = 0; mf < 4; mf++) {
      const int row = wm * 128 + 64 + mf * 16 + lr;
      af[mf] = *(const short8*)(Ak0 + row * 32 + ((lc ^ ((row >> 1) & 3)) * 8));
    }
    if (t + 1 < nt) STAGE(t + 1, 1);
    __builtin_amdgcn_s_barrier();
    asm volatile("s_waitcnt lgkmcnt(0)" ::: "memory");
    __builtin_amdgcn_sched_barrier(0);
    __builtin_amdgcn_s_setprio(1);
#pragma unroll
    for (int mf = 0; mf < 4; mf++)
#pragma unroll
      for (int nf = 0; nf < 3; nf++)
        acc[4 + mf][nf] = mfma16(af[mf], bf[nf], acc[4 + mf][nf]);
    __builtin_amdgcn_s_setprio(0);
    if (t + 1 < nt) {
      asm volatile("s_waitcnt vmcnt(4)" ::: "memory");
    } else {
      asm volatile("s_waitcnt vmcnt(0)" ::: "memory");
    }
    __builtin_amdgcn_s_barrier();

    // ---- P2
#pragma unroll
    for (int nf = 0; nf < 3; nf++) {
      const int row = wn * 48 + nf * 16 + lr;
      bf[nf] = *(const short8*)(Bk1 + row * 32 + ((lc ^ ((row >> 1) & 3)) * 8));
    }
#pragma unroll
    for (int mf = 0; mf < 4; mf++) {
      const int row = wm * 128 + mf * 16 + lr;
      af[mf] = *(const short8*)(Ak1 + row * 32 + ((lc ^ ((row >> 1) & 3)) * 8));
    }
    if (t + 1 < nt) STAGE(t + 1, 2);
    __builtin_amdgcn_s_barrier();
    asm volatile("s_waitcnt lgkmcnt(0)" ::: "memory");
    __builtin_amdgcn_sched_barrier(0);
    __builtin_amdgcn_s_setprio(1);
#pragma unroll
    for (int mf = 0; mf < 4; mf++)
#pragma unroll
      for (int nf = 0; nf < 3; nf++)
        acc[mf][nf] = mfma16(af[mf], bf[nf], acc[mf][nf]);
    __builtin_amdgcn_s_setprio(0);
    __builtin_amdgcn_s_barrier();

    // ---- P3
#pragma unroll
    for (int mf = 0; mf < 4; mf++) {
      const int row = wm * 128 + 64 + mf * 16 + lr;
      af[mf] = *(const short8*)(Ak1 + row * 32 + ((lc ^ ((row >> 1) & 3)) * 8));
    }
    if (t + 1 < nt) STAGE(t + 1, 3);
    __builtin_amdgcn_s_barrier();
    asm volatile("s_waitcnt lgkmcnt(0)" ::: "memory");
    __builtin_amdgcn_sched_barrier(0);
    __builtin_amdgcn_s_setprio(1);
#pragma unroll
    for (int mf = 0; mf < 4; mf++)
#pragma unroll
      for (int nf = 0; nf < 3; nf++)
        acc[4 + mf][nf] = mfma16(af[mf], bf[nf], acc[4 + mf][nf]);
    __builtin_amdgcn_s_setprio(0);
    if (t + 1 < nt) {
      asm volatile("s_waitcnt vmcnt(4)" ::: "memory");
    }
    __builtin_amdgcn_s_barrier();
  }

#pragma unroll
  for (int mfp = 0; mfp < 8; mfp++) {
#pragma unroll
    for (int nf = 0; nf < 3; nf++) {
      const int row = bm * 256 + wm * 128 + mfp * 16 + lc * 4;
      const int col = bn * 192 + wn * 48 + nf * 16 + lr;
#pragma unroll
      for (int r = 0; r < 4; r++)
        C[(size_t)(row + r) * N + col] = f2b(acc[mfp][nf][r]);
    }
  }
}

// ---------------- flash attention (causal GQA) — R9 config (best measured: 76us) ----
__global__ __launch_bounds__(256, 2) void attn_k(const ushort_t* __restrict__ Qb,
                                                 const ushort_t* __restrict__ Kb,
                                                 const ushort_t* __restrict__ Vf,
                                                 ushort_t* __restrict__ Yb) {
  __shared__ __attribute__((aligned(16))) ushort_t Ks[2][64 * 128];  // 32 KB
  const int tid = threadIdx.x;
  const int lane = tid & 63;
  const int w = tid >> 6;
  const int lr = lane & 15, lc = lane >> 4;
  const int gy = blockIdx.y;
  const int h = gy;
  const int b = blockIdx.z;
  const int kh = h >> 2;
  const int qc = b ? (15 - ((blockIdx.x + gy) & 15)) : ((blockIdx.x + gy) & 15);
  const int q0w = qc * 128 + w * 32;

  const ushort_t* Qp = Qb + (size_t)(b * 16 + h) * T_ * D_;
  const ushort_t* Kp = Kb + (size_t)(b * 4 + kh) * T_ * D_;
  const ushort_t* Vfb = Vf + (size_t)(b * 4 + kh) * 262144;

  const int st_row = tid >> 4;
  const int st_slot = tid & 15;

  short8 qf[2][4];
#pragma unroll
  for (int f = 0; f < 2; f++)
#pragma unroll
    for (int c = 0; c < 4; c++)
      qf[f][c] = *(const short8*)(Qp + (size_t)(q0w + f * 16 + lr) * D_ + c * 32 + lc * 8);

  f32x4 o[2][8];
#pragma unroll
  for (int f = 0; f < 2; f++)
#pragma unroll
    for (int n = 0; n < 8; n++) o[f][n] = (f32x4)(0.0f);
  float m[2] = {-1e30f, -1e30f}, l[2] = {0.0f, 0.0f};

  const int nt = 2 * qc + 2;

#pragma unroll
  for (int i = 0; i < 4; i++) {
    int row = i * 16 + st_row;
    async16(Kp + (size_t)row * D_ + (((st_slot - row) & 15) * 8),
            &Ks[0][0] + row * 128 + st_slot * 8);
  }

#pragma unroll 1
  for (int ti = 0; ti < nt; ti++) {
    __syncthreads();
    const int kv0 = ti * 64;
    if (ti + 1 < nt) {
      const ushort_t* Kn = Kp + (size_t)(kv0 + 64) * D_;
      ushort_t* dst = &Ks[(ti + 1) & 1][0];
#pragma unroll
      for (int i = 0; i < 4; i++) {
        int row = i * 16 + st_row;
        async16(Kn + (size_t)row * D_ + (((st_slot - row) & 15) * 8),
                dst + row * 128 + st_slot * 8);
      }
    }
    if (kv0 > q0w + 31) continue;
    const ushort_t* Kl = &Ks[ti & 1][0];
    const ushort_t* Vt0 = Vfb + (size_t)(ti * 2) * 4096;
    short8 vr0[8];
#pragma unroll
    for (int n = 0; n < 8; n++)
      vr0[n] = *(const short8*)(Vt0 + n * 512 + lane * 8);
    f32x4 s[2][4];
#pragma unroll
    for (int f = 0; f < 2; f++)
#pragma unroll
      for (int kj = 0; kj < 4; kj++) s[f][kj] = (f32x4)(0.0f);
    __builtin_amdgcn_s_setprio(1);
#pragma unroll
    for (int c = 0; c < 4; c++) {
      short8 kf[4];
#pragma unroll
      for (int kj = 0; kj < 4; kj++)
        kf[kj] = *(const short8*)(Kl + (kj * 16 + lr) * 128 + (((c * 4 + lc + lr) & 15) * 8));
#pragma unroll
      for (int f = 0; f < 2; f++)
#pragma unroll
        for (int kj = 0; kj < 4; kj++)
          s[f][kj] = mfma16(kf[kj], qf[f][c], s[f][kj]);
    }
    __builtin_amdgcn_s_setprio(0);
    const ushort_t* Vt1 = Vfb + (size_t)(ti * 2 + 1) * 4096;
    short8 vr1[8];
#pragma unroll
    for (int n = 0; n < 8; n++)
      vr1[n] = *(const short8*)(Vt1 + n * 512 + lane * 8);
    const bool maskt = (kv0 + 63 > q0w);
    union { unsigned u[4]; short8 v; } pa0[2], pa1[2];
#pragma unroll
    for (int f = 0; f < 2; f++) {
      const int q = q0w + f * 16 + lr;
      float pv[16];
      float mx = -1e30f;
      if (maskt) {
#pragma unroll
        for (int kj = 0; kj < 4; kj++)
#pragma unroll
          for (int r = 0; r < 4; r++) {
            float a = s[f][kj][r];
            if (kv0 + kj * 16 + lc * 4 + r > q) a = -1e30f;
            pv[kj * 4 + r] = a;
            mx = fmaxf(mx, a);
          }
      } else {
#pragma unroll
        for (int kj = 0; kj < 4; kj++)
#pragma unroll
          for (int r = 0; r < 4; r++) {
            float a = s[f][kj][r];
            pv[kj * 4 + r] = a;
            mx = fmaxf(mx, a);
          }
      }
      mx = fmaxf(mx, __shfl_xor(mx, 16));
      mx = fmaxf(mx, __shfl_xor(mx, 32));
      const bool need = __any(mx > m[f] + 8.0f);
      const float mn = need ? fmaxf(m[f], mx) : m[f];
      float rs = 0.0f;
#pragma unroll
      for (int i = 0; i < 16; i++) {
        pv[i] = exp2f(pv[i] - mn);
        rs += pv[i];
      }
      rs += __shfl_xor(rs, 16);
      rs += __shfl_xor(rs, 32);
#pragma unroll
      for (int kj = 0; kj < 2; kj++) {
        pa0[f].u[kj * 2] = cvtpk(pv[kj * 4], pv[kj * 4 + 1]);
        pa0[f].u[kj * 2 + 1] = cvtpk(pv[kj * 4 + 2], pv[kj * 4 + 3]);
        pa1[f].u[kj * 2] = cvtpk(pv[8 + kj * 4], pv[8 + kj * 4 + 1]);
        pa1[f].u[kj * 2 + 1] = cvtpk(pv[8 + kj * 4 + 2], pv[8 + kj * 4 + 3]);
      }
      if (need) {
        float al = exp2f(m[f] - mn);
        m[f] = mn;
        l[f] = l[f] * al + rs;
        float alT[4];
#pragma unroll
        for (int r = 0; r < 4; r++)
          alT[r] = __shfl(al, (lane & 48) | (lc * 4 + r));
#pragma unroll
        for (int n = 0; n < 8; n++)
#pragma unroll
          for (int r = 0; r < 4; r++) o[f][n][r] *= alT[r];
      } else {
        l[f] += rs;
      }
    }
    __builtin_amdgcn_s_setprio(1);
#pragma unroll
    for (int n = 0; n < 8; n++) {
      o[0][n] = mfma16(pa0[0].v, vr0[n], o[0][n]);
      o[1][n] = mfma16(pa0[1].v, vr0[n], o[1][n]);
    }
#pragma unroll
    for (int n = 0; n < 8; n++) {
      o[0][n] = mfma16(pa1[0].v, vr1[n], o[0][n]);
      o[1][n] = mfma16(pa1[1].v, vr1[n], o[1][n]);
    }
    __builtin_amdgcn_s_setprio(0);
  }
#pragma unroll
  for (int f = 0; f < 2; f++) {
    float inv = 1.0f / l[f];
    float invT[4];
#pragma unroll
    for (int r = 0; r < 4; r++)
      invT[r] = __shfl(inv, (lane & 48) | (lc * 4 + r));
#pragma unroll
    for (int n = 0; n < 8; n++)
#pragma unroll
      for (int r = 0; r < 4; r++) {
        int qo = q0w + f * 16 + lc * 4 + r;
        int d = n * 16 + lr;
        Yb[(size_t)(b * T_ + qo) * 2048 + h * 128 + d] = f2b(o[f][n][r] * invT[r]);
      }
  }
}

// ---------------- launch ----------------

extern "C" void kernel_launch(void* const* d_in, const int* in_sizes, int n_in,
                              void* d_out, int out_size, void* d_ws, size_t ws_size,
                              hipStream_t stream) {
  (void)in_sizes; (void)n_in; (void)out_size; (void)ws_size;
  const float* x = (const float*)d_in[0];
  const float* wq = (const float*)d_in[1];
  const float* wkv = (const float*)d_in[2];
  const float* wproj = (const float*)d_in[3];
  const float* omega = (const float*)d_in[4];
  float* out = (float*)d_out;
  char* ws = (char*)d_ws;

  ushort_t* xb     = (ushort_t*)(ws + 0);          // 4096x2048 bf16 = 16.8MB
  ushort_t* wqkvT  = (ushort_t*)(ws + 16777216);   // [3072][2048] bf16 (wqT then wkvT)
  ushort_t* wprojT = (ushort_t*)(ws + 29360128);   // 2048x2048 bf16
  ushort_t* QKVraw = (ushort_t*)(ws + 37748736);   // 4096x3072 bf16 = 25.2MB
  ushort_t* Qb     = (ushort_t*)(ws + 62914560);   // [b][h][t][d] bf16
  ushort_t* Kb     = (ushort_t*)(ws + 79691776);   // [b][kh][t][d] bf16
  ushort_t* Vf     = (ushort_t*)(ws + 83886080);   // V fragment-packed, 4MB
  ushort_t* Yb     = (ushort_t*)(ws + 88080384);   // 4096x2048 bf16
  float2*   tab    = (float2*)(ws + 104857600);    // 2048x64 float2 = 1MB

  // fused prep: convert | 3 transposes | rope table
  prep_a<<<18944, 256, 0, stream>>>(x, wq, wkv, wproj, omega, xb, wqkvT, wprojT, tab);

  // merged QKV projection via 256x192 8-phase (256 blocks = 100% CU fill)
  gemm256q<<<256, 512, 0, stream>>>(xb, wqkvT, QKVraw, 4096, 3072, 2048);

  // fused prep: rope-Q | rope-K | V fragment pre-pack
  prep_b<<<6144, 256, 0, stream>>>(QKVraw, tab, Qb, Kb, Vf);

  // attention: R9 config (best measured)
  attn_k<<<dim3(16, 16, 2), 256, 0, stream>>>(Qb, Kb, Vf, Yb);

  // output projection via 128x256 2-phase-per-Ktile (256 blocks, 16 MFMA/phase)
  gemm_proj<<<256, 512, 0, stream>>>(Yb, wprojT, out, 4096, 2048, 2048);
}